// Round 12
// baseline (118.598 us; speedup 1.0000x reference)
//
#include <hip/hip_runtime.h>

#define BB 2
#define NN 16384
#define KK 4096
#define CC 128
#define SS 32
#define SEG 32
#define SEGN (NN / SEG)      // 512 points per segment
#define BKK (BB * KK)        // 8192 queries

typedef float vfloat4 __attribute__((ext_vector_type(4)));

// ---------------------------------------------------------------------------
// Kernel A: transpose features [B][C][N] -> [B][N][C] + fused xyzw prep.
// UNCHANGED (absmax 0.0 verified rounds 2/4/6/7/8/10/11).
// ---------------------------------------------------------------------------
__global__ __launch_bounds__(256) void transpose_prep_kernel(
    const float* __restrict__ feat, const float* __restrict__ xyz,
    float* __restrict__ feat_t, float* __restrict__ xyzw)
{
    __shared__ float tile[64][133];
    const int b  = blockIdx.x >> 8;          // NN/64 = 256 tiles per batch
    const int n0 = (blockIdx.x & 255) * 64;
    const int t  = threadIdx.x;

    if (t < 64) {
        const int i = b * NN + n0 + t;
        const float* p = xyz + (size_t)i * 3;
        const float x = p[0], y = p[1], z = p[2];
        const float pp = __fadd_rn(__fadd_rn(__fmul_rn(x, x), __fmul_rn(y, y)),
                                   __fmul_rn(z, z));
        vfloat4 v = {x, y, z, pp};
        *(vfloat4*)(xyzw + (size_t)i * 4) = v;
    }

    const int ln = t & 63;
    const int cr = t >> 6;                   // 0..3
#pragma unroll
    for (int p = 0; p < 32; ++p) {
        const int c = p * 4 + cr;
        tile[ln][c] = feat[((size_t)b * CC + c) * NN + n0 + ln];
    }
    __syncthreads();

    const int cl = t & 31;
    const int ns = t >> 5;                   // 0..7
#pragma unroll
    for (int p = 0; p < 8; ++p) {
        const int n = ns + 8 * p;
        float* dst = feat_t + ((size_t)(b * NN + n0 + n)) * CC;
#pragma unroll
        for (int j = 0; j < 4; ++j)
            dst[cl + 32 * j] = tile[n][cl + 32 * j];
    }
}

// ---------------------------------------------------------------------------
// Kernel B: ball query v4 — segmented brute force, thread-per-query.
// Grid (32 query-blocks, SEG segments). Each thread owns one query (q in
// VGPRs); the point xw[n] is BLOCK-UNIFORM -> scalar s_load_dwordx4: zero
// vector-memory traffic, no LDS, no ballots, no tail divergence. Hits per
// (segment, query) recorded in ascending-n order (scan order), capped at 32.
// Float exprs EXACTLY match reference (no fma, left-assoc) -> absmax 0.0.
// ---------------------------------------------------------------------------
__global__ __launch_bounds__(256) void ball_seg_kernel(
    const float* __restrict__ xyzw,      // [B][N][4]
    const float* __restrict__ new_xyz,   // [B][K][3]
    int* __restrict__ hits,              // [SEG][BKK][SS]
    int* __restrict__ counts)            // [SEG][BKK]
{
    const int t  = threadIdx.x;
    const int qb = blockIdx.x;           // 0..31 (256 queries each)
    const int s  = blockIdx.y;           // 0..SEG-1
    const int qi = qb * 256 + t;
    const int b  = qb >> 4;              // 16 query-blocks per batch: uniform

    const float R2 = (float)(0.4 * 0.4);

    const float* q = new_xyz + (size_t)qi * 3;
    const float qx = q[0], qy = q[1], qz = q[2];
    const float qq = __fadd_rn(__fadd_rn(__fmul_rn(qx, qx), __fmul_rn(qy, qy)),
                               __fmul_rn(qz, qz));

    const vfloat4* xw = (const vfloat4*)xyzw + (size_t)b * NN;
    int* hrow = hits + ((size_t)s * BKK + qi) * SS;

    int cnt = 0;
    const int n0 = s * SEGN;
#pragma unroll 4
    for (int i = 0; i < SEGN; ++i) {
        const int n = n0 + i;
        const vfloat4 P = xw[n];         // uniform addr -> scalar load
        const float dot = __fadd_rn(
            __fadd_rn(__fmul_rn(qx, P.x), __fmul_rn(qy, P.y)),
            __fmul_rn(qz, P.z));
        const float d2 = __fsub_rn(__fadd_rn(qq, P.w), __fmul_rn(2.0f, dot));
        if (d2 < R2 && cnt < SS) {
            hrow[cnt] = n;
            ++cnt;
        }
    }
    counts[s * BKK + qi] = cnt;
}

// ---------------------------------------------------------------------------
// Kernel C: merge — one wave per query. Lane s<SEG loads counts[s][qi];
// shfl inclusive scan -> prefix; lane j<32 binary-searches its source
// segment, loads hits[s][qi][j - excl(s)], applies reference fill semantics
// (slots >= total get slot-0's value, or 0 if none), stores 32 coalesced.
// ---------------------------------------------------------------------------
__global__ __launch_bounds__(256) void merge_kernel(
    const int* __restrict__ hits,        // [SEG][BKK][SS]
    const int* __restrict__ counts,      // [SEG][BKK]
    int* __restrict__ idx_buf)           // [BKK][SS]
{
    const int wave = threadIdx.x >> 6;
    const int lane = threadIdx.x & 63;
    const int qi   = blockIdx.x * 4 + wave;

    int c = (lane < SEG) ? counts[lane * BKK + qi] : 0;
    // Inclusive scan across lanes (segment prefix).
#pragma unroll
    for (int d = 1; d < 64; d <<= 1) {
        const int u = __shfl_up(c, d);
        if (lane >= d) c += u;
    }
    const int total = __shfl(c, SEG - 1);

    // Lane j = output slot j: find s = min{s : incl[s] > j}.
    int lo = 0;
#pragma unroll
    for (int step = 16; step >= 1; step >>= 1) {
        const int cand = lo + step;                  // <= 31
        const int pv = __shfl(c, cand - 1);          // incl prefix of cand-1
        if (lane >= pv) lo = cand;
    }
    const int pex  = __shfl(c, (lo > 0) ? lo - 1 : 0);
    const int excl = (lo > 0) ? pex : 0;
    const int off  = lane - excl;

    int v = 0;
    if (lane < SS && lane < total)
        v = hits[((size_t)lo * BKK + qi) * SS + off];

    int first = __shfl(v, 0);
    if (total == 0) first = 0;
    const int outv = (lane < total) ? v : first;

    if (lane < SS) idx_buf[(size_t)qi * SS + lane] = outv;
}

// ---------------------------------------------------------------------------
// Kernel D: grouping. UNCHANGED single-copy form (G~7us gather + W~24us
// stores, 0 bank conflicts — validated round 10).
// ---------------------------------------------------------------------------
__global__ __launch_bounds__(256) void group_kernel(
    const float* __restrict__ xyzw,      // [B][N][4]
    const float* __restrict__ new_xyz,   // [B][K][3]
    const float* __restrict__ feat_t,    // [B][N][C]
    const int*   __restrict__ idx_buf,   // [B*K][S]
    float* __restrict__ out)             // [B][3][K][S] ++ [B][C][K][S]
{
    __shared__ float tile[SS * CC];      // 32 rows x 512B, linear, chunk-swizzled
    __shared__ float txyz[3][SS];

    const int t    = threadIdx.x;
    const int l    = t & 63;
    const int w    = t >> 6;             // wave 0..3
    const int bk   = blockIdx.x;
    const int b    = bk >> 12;
    const int k    = bk & (KK - 1);
    const int half = l >> 5;             // 0..1
    const int cl   = l & 31;             // chunk slot within row

#pragma unroll
    for (int p = 0; p < 4; ++p) {
        const int r = 8 * w + 2 * p;                 // wave-uniform row base
        const int s = r + half;
        const int n = idx_buf[bk * SS + s];
        const int chunk = cl ^ ((s >> 2) & 7);
        const float* src = feat_t + ((size_t)(b * NN + n)) * CC + 4 * chunk;
        __builtin_amdgcn_global_load_lds(
            (const __attribute__((address_space(1))) void*)src,
            (__attribute__((address_space(3))) void*)(tile + r * CC),
            16, 0, 0);
    }

    if (t < SS) {
        const int n = idx_buf[bk * SS + t];
        const float* q = new_xyz + (size_t)bk * 3;
        const vfloat4 wv = *((const vfloat4*)xyzw + (size_t)b * NN + n);
        txyz[0][t] = (wv.x - q[0]) / 0.4f;
        txyz[1][t] = (wv.y - q[1]) / 0.4f;
        txyz[2][t] = (wv.z - q[2]) / 0.4f;
    }

    __syncthreads();   // drains vmcnt(0): all DMAs + txyz visible

    float* out_xyz  = out;
    float* out_feat = out + (size_t)BB * 3 * KK * SS;

    const int sq = t & 7;
    const int c0 = t >> 3;               // 0..31
#pragma unroll
    for (int p = 0; p < 4; ++p) {
        const int c  = c0 + 32 * p;
        const int co = (((c >> 2) ^ sq) << 2) + (c & 3);   // un-swizzled col
        vfloat4 v;
        v.x = tile[(4 * sq + 0) * CC + co];
        v.y = tile[(4 * sq + 1) * CC + co];
        v.z = tile[(4 * sq + 2) * CC + co];
        v.w = tile[(4 * sq + 3) * CC + co];
        __builtin_nontemporal_store(
            v, (vfloat4*)(out_feat + (((size_t)(b * CC + c) * KK + k) * SS + 4 * sq)));
    }

    if (t < 24) {
        const int d   = t >> 3;
        const int sq2 = t & 7;
        const vfloat4 v = *(vfloat4*)&txyz[d][4 * sq2];
        __builtin_nontemporal_store(
            v, (vfloat4*)(out_xyz + (((size_t)(b * 3 + d) * KK + k) * SS + 4 * sq2)));
    }
}

extern "C" void kernel_launch(void* const* d_in, const int* in_sizes, int n_in,
                              void* d_out, int out_size, void* d_ws, size_t ws_size,
                              hipStream_t stream) {
    const float* xyz     = (const float*)d_in[0];   // [2][16384][3]
    const float* new_xyz = (const float*)d_in[1];   // [2][4096][3]
    const float* feat    = (const float*)d_in[2];   // [2][128][16384]
    float* out = (float*)d_out;

    // Workspace (17.5 MB): idx_buf 1MB | xyzw 0.5MB | feat_t 16MB
    int*   idx_buf = (int*)d_ws;
    float* xyzw    = (float*)((char*)d_ws + (1 << 20));
    float* feat_t  = (float*)((char*)d_ws + (1 << 20) + (512 << 10));

    // Segment scratch lives in d_out's feature region (34.5 MB of 134 MB);
    // group_kernel overwrites every byte of d_out afterwards.
    int* hits   = (int*)(out + (size_t)BB * 3 * KK * SS);   // [SEG][BKK][SS] 33.5MB
    int* counts = hits + (size_t)SEG * BKK * SS;            // [SEG][BKK] 1MB

    transpose_prep_kernel<<<dim3(BB * (NN / 64)), dim3(256), 0, stream>>>(
        feat, xyz, feat_t, xyzw);

    ball_seg_kernel<<<dim3(BKK / 256, SEG), dim3(256), 0, stream>>>(
        xyzw, new_xyz, hits, counts);

    merge_kernel<<<dim3(BKK / 4), dim3(256), 0, stream>>>(
        hits, counts, idx_buf);

    group_kernel<<<dim3(BKK), dim3(256), 0, stream>>>(
        xyzw, new_xyz, feat_t, idx_buf, out);
}